// Round 2
// baseline (72.269 us; speedup 1.0000x reference)
//
#include <hip/hip_runtime.h>
#include <hip/hip_bf16.h>

#define RCR 5.2f
#define RCA 3.5f
#define PI_F 3.14159265358979323846f

// One block per central atom (c,i). 384 threads:
//   lanes 0..63   -> radial output slots (4 species x 16 shells)
//   lanes 64..383 -> angular output slots (10 pair-ids x 4 shells x 8 angles)
__global__ __launch_bounds__(384)
void aev_kernel(const int* __restrict__ species,
                const float* __restrict__ coords,
                float* __restrict__ out)
{
    const int blk = blockIdx.x;     // c*64 + i
    const int c   = blk >> 6;
    const int i   = blk & 63;
    const int tid = threadIdx.x;

    __shared__ float sxx[64], syy[64], szz[64];
    __shared__ int   ssp[64];
    __shared__ float nrx[64], nry[64], nrz[64];   // x_i - x_j
    __shared__ float nd[64], ninv[64], nfcR[64], nfcA[64];
    __shared__ int   alist[64];
    __shared__ int   acount;
    __shared__ int   pairjk[2016];                // worst case 63*62/2 = 1953

    if (tid == 0) acount = 0;
    if (tid < 64) {
        const int j = tid;
        const int base = (c * 64 + j) * 3;
        sxx[j] = coords[base + 0];
        syy[j] = coords[base + 1];
        szz[j] = coords[base + 2];
        ssp[j] = species[c * 64 + j];
    }
    __syncthreads();

    if (tid < 64) {
        const int j = tid;
        float rx = sxx[i] - sxx[j];
        float ry = syy[i] - syy[j];
        float rz = szz[i] - szz[j];
        float d  = sqrtf(rx*rx + ry*ry + rz*rz);
        bool valid = (j != i) && (ssp[j] != -1);
        float fr = 0.f, fa = 0.f, inv = 0.f;
        if (valid) {
            inv = 1.0f / fmaxf(d, 1e-8f);
            if (d <= RCR) fr = 0.5f * __cosf(PI_F * d * (1.0f/RCR)) + 0.5f;
            if (d <= RCA) {
                fa = 0.5f * __cosf(PI_F * d * (1.0f/RCA)) + 0.5f;
                int pos = atomicAdd(&acount, 1);
                alist[pos] = j;
            }
        }
        nrx[j] = rx; nry[j] = ry; nrz[j] = rz;
        nd[j] = d; ninv[j] = inv; nfcR[j] = fr; nfcA[j] = fa;
    }
    __syncthreads();

    const int n = acount;
    if (tid < n) {                         // build packed pair list (row tid)
        int a = tid;
        int base = a * (n - 1) - (a * (a - 1)) / 2;
        int ja = alist[a];
        for (int b = a + 1; b < n; ++b)
            pairjk[base + (b - a - 1)] = (ja << 8) | alist[b];
    }
    __syncthreads();

    const int np = (n * (n - 1)) >> 1;
    const long ob = (long)(c * 64 + i) * 384;

    if (tid < 64) {
        // ----- radial slot: species s, shell r -----
        const int s = tid >> 4, r = tid & 15;
        const float shf = 0.9f + 0.26875f * (float)r;
        float acc = 0.f;
        for (int j = 0; j < 64; ++j) {
            if (ssp[j] == s) {
                float u = nd[j] - shf;
                acc += 0.25f * __expf(-16.f * u * u) * nfcR[j];
            }
        }
        out[ob + tid] = acc;
    } else {
        // ----- angular slot: pair-id pid, shell aa, angle bin z -----
        const int slot = tid - 64;
        const int pid  = slot >> 5;
        const int aa   = (slot >> 3) & 3;
        const int z    = slot & 7;
        const float shfa = 0.9f + 0.65f * (float)aa;
        const float shfz = PI_F / 16.f + (PI_F / 8.f) * (float)z;
        const float czv = __cosf(shfz);
        const float szv = __sinf(shfz);
        float acc = 0.f;
        for (int p = 0; p < np; ++p) {
            int jk = pairjk[p];
            int j = jk >> 8, k = jk & 255;
            int s1 = ssp[j], s2 = ssp[k];
            int mn = min(s1, s2), mx = max(s1, s2);
            int ppid = ((mn * (7 - mn)) >> 1) + mx;
            float dot = nrx[j]*nrx[k] + nry[j]*nry[k] + nrz[j]*nrz[k];
            float ca  = 0.95f * dot * ninv[j] * ninv[k];
            float sa  = sqrtf(fmaxf(0.f, 1.f - ca * ca));
            float dm  = 0.5f * (nd[j] + nd[k]);
            float fprod = 2.f * nfcA[j] * nfcA[k];
            float cd = ca * czv + sa * szv;
            float t  = 0.5f + 0.5f * cd;
            t = t * t; t = t * t; t = t * t; t = t * t; t = t * t;   // ^32
            float u  = dm - shfa;
            float f2 = __expf(-8.f * u * u);
            float val = t * f2 * fprod;
            acc += (ppid == pid) ? val : 0.f;
        }
        out[ob + 64 + slot] = acc;
    }
}

extern "C" void kernel_launch(void* const* d_in, const int* in_sizes, int n_in,
                              void* d_out, int out_size, void* d_ws, size_t ws_size,
                              hipStream_t stream) {
    const int* species   = (const int*)d_in[0];
    const float* coords  = (const float*)d_in[1];
    float* out           = (float*)d_out;
    aev_kernel<<<dim3(16 * 64), dim3(384), 0, stream>>>(species, coords, out);
}

// Round 3
// 66.207 us; speedup vs baseline: 1.0916x; 1.0916x over previous
//
#include <hip/hip_runtime.h>

#define RCR 5.2f
#define RCA 3.5f
#define PI_F 3.14159265358979323846f

// One wave (64 threads) per central atom (c,i). 1024 blocks.
// Lane j computes neighbor-j data; ballot-compacted radial & angular lists;
// radial: lane-per-slot over ~10 compacted neighbors;
// angular: 2 pairs/iter, 32 lanes per pair (one (shell,angle) slot each).
__global__ __launch_bounds__(64)
void aev_kernel(const int* __restrict__ species,
                const float* __restrict__ coords,
                float* __restrict__ out)
{
    const int blk = blockIdx.x;     // c*64 + i
    const int c   = blk >> 6;
    const int i   = blk & 63;
    const int l   = threadIdx.x;    // 0..63, lane == neighbor index

    // ---- per-neighbor data in registers ----
    const int gbase = (c * 64 + l) * 3;
    float x = coords[gbase + 0];
    float y = coords[gbase + 1];
    float z = coords[gbase + 2];
    int  sp = species[c * 64 + l];

    float xi = __shfl(x, i);
    float yi = __shfl(y, i);
    float zi = __shfl(z, i);

    float rx = xi - x, ry = yi - y, rz = zi - z;
    float d  = sqrtf(rx * rx + ry * ry + rz * rz);
    bool valid  = (l != i) && (sp != -1);
    bool rvalid = valid && (d <= RCR);
    bool avalid = valid && (d <= RCA);

    __shared__ float cx[64], cy[64], cz[64], cd_[64], cinv[64], cfa[64];
    __shared__ int   csp[64];
    __shared__ float rd[64], rfc[64];
    __shared__ int   rsp[64];
    __shared__ int   pairab[1953];     // worst case 63*62/2
    __shared__ float acc[320];

    for (int t = l; t < 320; t += 64) acc[t] = 0.f;

    unsigned long long rmask = __ballot(rvalid);
    unsigned long long amask = __ballot(avalid);
    const int nr = __popcll(rmask);
    const int n  = __popcll(amask);
    const unsigned long long below = (l == 0) ? 0ull : (~0ull >> (64 - l));

    if (rvalid) {
        int pos = __popcll(rmask & below);
        rd[pos]  = d;
        rfc[pos] = 0.5f * __cosf(PI_F * d * (1.0f / RCR)) + 0.5f;
        rsp[pos] = sp;
    }
    if (avalid) {
        int pos = __popcll(amask & below);
        cx[pos] = rx; cy[pos] = ry; cz[pos] = rz;
        cd_[pos]  = d;
        cinv[pos] = 1.0f / fmaxf(d, 1e-8f);
        cfa[pos]  = 0.5f * __cosf(PI_F * d * (1.0f / RCA)) + 0.5f;
        csp[pos]  = sp;
    }
    // pair list over compacted angular indices (no LDS dependency)
    if (l < n) {
        int a = l;
        int base = a * (n - 1) - (a * (a - 1)) / 2;
        for (int b = a + 1; b < n; ++b)
            pairab[base + (b - a - 1)] = (a << 6) | b;
    }
    __syncthreads();

    // ---- radial: lane l owns slot (species s = l>>4, shell r = l&15) ----
    const int   s   = l >> 4;
    const float shf = 0.9f + 0.26875f * (float)(l & 15);
    float racc = 0.f;
    for (int m = 0; m < nr; ++m) {
        float dd   = rd[m] - shf;
        float term = 0.25f * __expf(-16.f * dd * dd) * rfc[m];
        racc += (rsp[m] == s) ? term : 0.f;
    }

    // ---- angular: 2 pairs per iteration, 32 lanes per pair ----
    const int   sub  = l & 31;                         // aa*8 + z
    const float shfa = 0.9f + 0.65f * (float)(sub >> 3);
    const float shfz = PI_F / 16.f + (PI_F / 8.f) * (float)(sub & 7);
    const float czv  = __cosf(shfz);
    const float szv  = __sinf(shfz);
    const int   np   = (n * (n - 1)) >> 1;
    const int   half = l >> 5;
    for (int p0 = 0; p0 < np; p0 += 2) {
        int p = p0 + half;
        if (p < np) {
            int ab = pairab[p];
            int a = ab >> 6, b = ab & 63;
            float dot = cx[a] * cx[b] + cy[a] * cy[b] + cz[a] * cz[b];
            float ca  = 0.95f * dot * cinv[a] * cinv[b];
            float sa  = sqrtf(fmaxf(0.f, 1.f - ca * ca));
            float dm  = 0.5f * (cd_[a] + cd_[b]);
            float fprod = 2.f * cfa[a] * cfa[b];
            int s1 = csp[a], s2 = csp[b];
            int mn = min(s1, s2), mx = max(s1, s2);
            int pid = ((mn * (7 - mn)) >> 1) + mx;
            float cdz = ca * czv + sa * szv;
            float t = 0.5f + 0.5f * cdz;
            t = t * t; t = t * t; t = t * t; t = t * t; t = t * t;  // ^32
            float u = dm - shfa;
            float val = t * __expf(-8.f * u * u) * fprod;
            atomicAdd(&acc[pid * 32 + sub], val);
        }
    }
    __syncthreads();

    // ---- epilogue: 384 floats, coalesced ----
    const long ob = (long)blk * 384;
    out[ob + l] = racc;
    #pragma unroll
    for (int t = 0; t < 5; ++t)
        out[ob + 64 + t * 64 + l] = acc[t * 64 + l];
}

extern "C" void kernel_launch(void* const* d_in, const int* in_sizes, int n_in,
                              void* d_out, int out_size, void* d_ws, size_t ws_size,
                              hipStream_t stream) {
    const int* species  = (const int*)d_in[0];
    const float* coords = (const float*)d_in[1];
    float* out          = (float*)d_out;
    aev_kernel<<<dim3(16 * 64), dim3(64), 0, stream>>>(species, coords, out);
}